// Round 5
// baseline (1450.805 us; speedup 1.0000x reference)
//
#include <hip/hip_runtime.h>

#define IN_C 300
#define OUT_C 200
#define NEG_SLOPE 0.2f
#define BM 80
#define BK 20

static inline int cdiv(long a, int b) { return (int)((a + b - 1) / b); }

// ---------------- utility ----------------
__global__ __launch_bounds__(256)
void zero_int_kernel(int* __restrict__ p, int n) {
  int i = blockIdx.x * blockDim.x + threadIdx.x;
  if (i < n) p[i] = 0;
}

__device__ __forceinline__ void edge_sd(const int* __restrict__ src,
                                        const int* __restrict__ dst,
                                        int i, int E, int& s, int& d) {
  if (i < E) { s = src[i]; d = dst[i]; } else { s = d = i - E; }
}

// ---------------- CSR build ----------------
__global__ __launch_bounds__(256)
void hist_kernel(const int* __restrict__ src, const int* __restrict__ dst,
                 int E, int ET, int* __restrict__ counts) {
  int i = blockIdx.x * blockDim.x + threadIdx.x;
  if (i >= ET) return;
  int s, d; edge_sd(src, dst, i, E, s, d);
  atomicAdd(counts + d, 1);
}

// inclusive scan, 1024 elems/block (256 thr x 4). out = rowptr+1.
__global__ __launch_bounds__(256)
void scan_a_kernel(const int* __restrict__ in, int n, int* __restrict__ out,
                   int* __restrict__ bsums) {
  __shared__ int lds[256];
  int t = threadIdx.x;
  int base = blockIdx.x * 1024 + t * 4;
  int v0 = (base + 0 < n) ? in[base + 0] : 0;
  int v1 = (base + 1 < n) ? in[base + 1] : 0;
  int v2 = (base + 2 < n) ? in[base + 2] : 0;
  int v3 = (base + 3 < n) ? in[base + 3] : 0;
  int s1 = v0 + v1, s2 = s1 + v2, s3 = s2 + v3;
  lds[t] = s3;
  __syncthreads();
  for (int o = 1; o < 256; o <<= 1) {
    int x = (t >= o) ? lds[t - o] : 0;
    __syncthreads();
    lds[t] += x;
    __syncthreads();
  }
  int pre = (t > 0) ? lds[t - 1] : 0;
  if (base + 0 < n) out[base + 0] = pre + v0;
  if (base + 1 < n) out[base + 1] = pre + s1;
  if (base + 2 < n) out[base + 2] = pre + s2;
  if (base + 3 < n) out[base + 3] = pre + s3;
  if (t == 255) bsums[blockIdx.x] = lds[255];
}

__global__ __launch_bounds__(256)
void scan_b_kernel(int* __restrict__ bs, int nb) {
  __shared__ int lds[256];
  int t = threadIdx.x;
  lds[t] = (t < nb) ? bs[t] : 0;
  __syncthreads();
  for (int o = 1; o < 256; o <<= 1) {
    int x = (t >= o) ? lds[t - o] : 0;
    __syncthreads();
    lds[t] += x;
    __syncthreads();
  }
  if (t < nb) bs[t] = lds[t];
}

__global__ __launch_bounds__(256)
void scan_c_kernel(int* __restrict__ out, int n, const int* __restrict__ bs) {
  int i = blockIdx.x * blockDim.x + threadIdx.x;
  if (i >= n) return;
  int b = i >> 10;
  if (b > 0) out[i] += bs[b - 1];
}

__global__ __launch_bounds__(256)
void fill_kernel(const int* __restrict__ src, const int* __restrict__ dst,
                 int E, int ET, const int* __restrict__ rowptr,
                 int* __restrict__ cursor, int* __restrict__ csr_src) {
  int i = blockIdx.x * blockDim.x + threadIdx.x;
  if (i >= ET) return;
  int s, d; edge_sd(src, dst, i, E, s, d);
  int pos = rowptr[d] + atomicAdd(cursor + d, 1);
  csr_src[pos] = s;
}

// ---------------- dense projection + fused alpha dots ----------------
// C[N,OUT_C] = A[N,K] @ W[K,OUT_C]. Block: BM=80 rows, BK=20.
// 256 threads; t<250: (rg,cg)=(t/25,t%25), 8 rows x 8 cols
// (cols cg*4..+3 and 100+cg*4..+3 -> 16B-stride conflict-free LDS reads).
// Epilogue computes asN/adN via LDS reduction (alphas kernel fused away).
__global__ __launch_bounds__(256)
void gemm_tiled_kernel(const float* __restrict__ A, const float* __restrict__ W,
                       float* __restrict__ C, int K,
                       const float* __restrict__ a_src, const float* __restrict__ a_dst,
                       float* __restrict__ asN, float* __restrict__ adN) {
  __shared__ float As[BM][BK];      // 6.4 KB, rows 80 B: staged contiguously
  __shared__ float Ws[BK][OUT_C];   // 16 KB
  __shared__ float red_s[BM], red_d[BM];
  int t = threadIdx.x;
  int rg = t / 25;                  // 0..9 (t>=250: load-only)
  int cg = t % 25;
  long row0 = (long)blockIdx.x * BM;

  float4 accA[8], accB[8];
  #pragma unroll
  for (int i = 0; i < 8; ++i) {
    accA[i] = make_float4(0.f, 0.f, 0.f, 0.f);
    accB[i] = make_float4(0.f, 0.f, 0.f, 0.f);
  }

  for (int kc = 0; kc < K; kc += BK) {
    // stage A tile: 400 float4 (contiguous per row, conflict-free)
    for (int idx = t; idx < BM * (BK / 4); idx += 256) {
      int r = idx / (BK / 4), c = idx % (BK / 4);
      *(float4*)&As[r][c * 4] = *(const float4*)(A + (row0 + r) * K + kc + c * 4);
    }
    // stage W tile: 1000 float4
    for (int idx = t; idx < BK * (OUT_C / 4); idx += 256) {
      int r = idx / (OUT_C / 4), c = idx % (OUT_C / 4);
      *(float4*)&Ws[r][c * 4] = *(const float4*)(W + (long)(kc + r) * OUT_C + c * 4);
    }
    __syncthreads();
    if (t < 250) {
      #pragma unroll
      for (int kk = 0; kk < BK; kk += 4) {
        float4 wA0 = *(float4*)&Ws[kk + 0][cg * 4];
        float4 wA1 = *(float4*)&Ws[kk + 1][cg * 4];
        float4 wA2 = *(float4*)&Ws[kk + 2][cg * 4];
        float4 wA3 = *(float4*)&Ws[kk + 3][cg * 4];
        float4 wB0 = *(float4*)&Ws[kk + 0][100 + cg * 4];
        float4 wB1 = *(float4*)&Ws[kk + 1][100 + cg * 4];
        float4 wB2 = *(float4*)&Ws[kk + 2][100 + cg * 4];
        float4 wB3 = *(float4*)&Ws[kk + 3][100 + cg * 4];
        #pragma unroll
        for (int i = 0; i < 8; ++i) {
          float4 a = *(float4*)&As[rg * 8 + i][kk];
          accA[i].x += a.x * wA0.x + a.y * wA1.x + a.z * wA2.x + a.w * wA3.x;
          accA[i].y += a.x * wA0.y + a.y * wA1.y + a.z * wA2.y + a.w * wA3.y;
          accA[i].z += a.x * wA0.z + a.y * wA1.z + a.z * wA2.z + a.w * wA3.z;
          accA[i].w += a.x * wA0.w + a.y * wA1.w + a.z * wA2.w + a.w * wA3.w;
          accB[i].x += a.x * wB0.x + a.y * wB1.x + a.z * wB2.x + a.w * wB3.x;
          accB[i].y += a.x * wB0.y + a.y * wB1.y + a.z * wB2.y + a.w * wB3.y;
          accB[i].z += a.x * wB0.z + a.y * wB1.z + a.z * wB2.z + a.w * wB3.z;
          accB[i].w += a.x * wB0.w + a.y * wB1.w + a.z * wB2.w + a.w * wB3.w;
        }
      }
    }
    __syncthreads();
  }

  if (t < BM) { red_s[t] = 0.f; red_d[t] = 0.f; }
  __syncthreads();

  if (t < 250) {
    float4 sA = *(const float4*)(a_src + cg * 4);
    float4 sB = *(const float4*)(a_src + 100 + cg * 4);
    float4 dA = *(const float4*)(a_dst + cg * 4);
    float4 dB = *(const float4*)(a_dst + 100 + cg * 4);
    #pragma unroll
    for (int i = 0; i < 8; ++i) {
      long row = row0 + rg * 8 + i;
      *(float4*)(C + row * OUT_C + cg * 4) = accA[i];
      *(float4*)(C + row * OUT_C + 100 + cg * 4) = accB[i];
      float ps = accA[i].x * sA.x + accA[i].y * sA.y + accA[i].z * sA.z + accA[i].w * sA.w
               + accB[i].x * sB.x + accB[i].y * sB.y + accB[i].z * sB.z + accB[i].w * sB.w;
      float pd = accA[i].x * dA.x + accA[i].y * dA.y + accA[i].z * dA.z + accA[i].w * dA.w
               + accB[i].x * dB.x + accB[i].y * dB.y + accB[i].z * dB.z + accB[i].w * dB.w;
      atomicAdd(&red_s[rg * 8 + i], ps);
      atomicAdd(&red_d[rg * 8 + i], pd);
    }
  }
  __syncthreads();
  if (t < BM) {
    asN[row0 + t] = red_s[t];
    adN[row0 + t] = red_d[t];
  }
}

// ---------------- fused segment-softmax + gather-aggregate + bias + relu ----
// One wave per destination node. Fast path (deg<=64): per-lane edge scores in
// registers, shuffle softmax, float4 gather unrolled x2.
__global__ __launch_bounds__(256)
void gather_agg_kernel(const float* __restrict__ h, const float* __restrict__ asN,
                       const float* __restrict__ adN, const int* __restrict__ rowptr,
                       const int* __restrict__ csr_src, const float* __restrict__ bias,
                       float* __restrict__ out, int N) {
  int wid = (int)(((long)blockIdx.x * blockDim.x + threadIdx.x) >> 6);
  int lane = threadIdx.x & 63;
  if (wid >= N) return;
  int start = rowptr[wid], end = rowptr[wid + 1];
  int deg = end - start;
  float ad = adN[wid];
  const float4* h4 = (const float4*)h;

  float4 acc = make_float4(0.f, 0.f, 0.f, 0.f);

  if (deg <= 64) {
    // per-lane score
    int s_l = (lane < deg) ? csr_src[start + lane] : 0;
    float sc = -1e30f;
    if (lane < deg) {
      float v = asN[s_l] + ad;
      sc = v > 0.f ? v : NEG_SLOPE * v;
    }
    float m = sc;
    #pragma unroll
    for (int o = 32; o > 0; o >>= 1) m = fmaxf(m, __shfl_xor(m, o));
    float ex = (lane < deg) ? __expf(sc - m) : 0.f;
    float se = ex;
    #pragma unroll
    for (int o = 32; o > 0; o >>= 1) se += __shfl_xor(se, o);
    float w_l = ex / se;

    int j = 0;
    for (; j + 2 <= deg; j += 2) {
      float w0 = __shfl(w_l, j), w1 = __shfl(w_l, j + 1);
      int   s0 = __shfl(s_l, j), s1 = __shfl(s_l, j + 1);
      if (lane < OUT_C / 4) {
        float4 r0 = h4[(long)s0 * (OUT_C / 4) + lane];
        float4 r1 = h4[(long)s1 * (OUT_C / 4) + lane];
        acc.x += w0 * r0.x + w1 * r1.x;
        acc.y += w0 * r0.y + w1 * r1.y;
        acc.z += w0 * r0.z + w1 * r1.z;
        acc.w += w0 * r0.w + w1 * r1.w;
      }
    }
    if (j < deg) {
      float w0 = __shfl(w_l, j);
      int   s0 = __shfl(s_l, j);
      if (lane < OUT_C / 4) {
        float4 r0 = h4[(long)s0 * (OUT_C / 4) + lane];
        acc.x += w0 * r0.x; acc.y += w0 * r0.y;
        acc.z += w0 * r0.z; acc.w += w0 * r0.w;
      }
    }
  } else {
    // generic path (rare): 3 passes
    float m = -1e30f;
    for (int j = start + lane; j < end; j += 64) {
      float v = asN[csr_src[j]] + ad;
      v = v > 0.f ? v : NEG_SLOPE * v;
      m = fmaxf(m, v);
    }
    #pragma unroll
    for (int o = 32; o > 0; o >>= 1) m = fmaxf(m, __shfl_xor(m, o));
    float se = 0.f;
    for (int j = start + lane; j < end; j += 64) {
      float v = asN[csr_src[j]] + ad;
      v = v > 0.f ? v : NEG_SLOPE * v;
      se += __expf(v - m);
    }
    #pragma unroll
    for (int o = 32; o > 0; o >>= 1) se += __shfl_xor(se, o);
    float inv = 1.0f / se;
    for (int j = start; j < end; ++j) {
      int s = csr_src[j];
      float v = asN[s] + ad;
      v = v > 0.f ? v : NEG_SLOPE * v;
      float w = __expf(v - m) * inv;
      if (lane < OUT_C / 4) {
        float4 r = h4[(long)s * (OUT_C / 4) + lane];
        acc.x += w * r.x; acc.y += w * r.y;
        acc.z += w * r.z; acc.w += w * r.w;
      }
    }
  }

  if (lane < OUT_C / 4) {
    float4 bb = ((const float4*)bias)[lane];
    float4 o4;
    o4.x = fmaxf(acc.x + bb.x, 0.f);
    o4.y = fmaxf(acc.y + bb.y, 0.f);
    o4.z = fmaxf(acc.z + bb.z, 0.f);
    o4.w = fmaxf(acc.w + bb.w, 0.f);
    ((float4*)out)[(long)wid * (OUT_C / 4) + lane] = o4;
  }
}

// ---------------- driver ----------------
static void run_layer(const float* xin, int K, const float* W,
                      const float* a_s, const float* a_d, const float* b,
                      const int* rowptr, const int* csr_src, int N,
                      float* hbuf, float* asN, float* adN, float* outbuf,
                      hipStream_t stream) {
  gemm_tiled_kernel<<<N / BM, 256, 0, stream>>>(xin, W, hbuf, K, a_s, a_d, asN, adN);
  gather_agg_kernel<<<cdiv((long)N * 64, 256), 256, 0, stream>>>(
      hbuf, asN, adN, rowptr, csr_src, b, outbuf, N);
}

extern "C" void kernel_launch(void* const* d_in, const int* in_sizes, int n_in,
                              void* d_out, int out_size, void* d_ws, size_t ws_size,
                              hipStream_t stream) {
  const float* x   = (const float*)d_in[0];
  const float* W0  = (const float*)d_in[1];
  const float* as0 = (const float*)d_in[2];
  const float* ad0 = (const float*)d_in[3];
  const float* b0  = (const float*)d_in[4];
  const float* W1  = (const float*)d_in[5];
  const float* as1 = (const float*)d_in[6];
  const float* ad1 = (const float*)d_in[7];
  const float* b1  = (const float*)d_in[8];
  const int*   ei  = (const int*)d_in[9];

  const int N  = in_sizes[0] / IN_C;
  const int E  = in_sizes[9] / 2;
  const int ET = E + N;
  const int* src = ei;
  const int* dst = ei + E;

  float* out = (float*)d_out;

  char* ws = (char*)d_ws;
  float* hbuf   = (float*)ws;                                  // N*OUT_C
  float* asN    = (float*)(ws + (size_t)N * OUT_C * 4);        // N
  float* adN    = asN + N;                                     // N
  int*   rowptr = (int*)(adN + N);                             // N+1
  int*   counts = rowptr + (N + 1);                            // N (also cursor)
  int*   bsums  = counts + N;                                  // 256
  int*   csrsrc = bsums + 256;                                 // ET

  const int nb = cdiv(N, 1024);

  // ---- one-time CSR build (shared by both layers) ----
  zero_int_kernel<<<cdiv(N, 256), 256, 0, stream>>>(counts, N);
  hist_kernel<<<cdiv(ET, 256), 256, 0, stream>>>(src, dst, E, ET, counts);
  scan_a_kernel<<<nb, 256, 0, stream>>>(counts, N, rowptr + 1, bsums);
  scan_b_kernel<<<1, 256, 0, stream>>>(bsums, nb);
  scan_c_kernel<<<cdiv(N, 256), 256, 0, stream>>>(rowptr + 1, N, bsums);
  zero_int_kernel<<<1, 256, 0, stream>>>(rowptr, 1);
  zero_int_kernel<<<cdiv(N, 256), 256, 0, stream>>>(counts, N);  // reuse as cursor
  fill_kernel<<<cdiv(ET, 256), 256, 0, stream>>>(src, dst, E, ET, rowptr, counts, csrsrc);

  // ---- layer 0: x -> out ----
  run_layer(x, IN_C, W0, as0, ad0, b0, rowptr, csrsrc, N, hbuf, asN, adN, out, stream);
  // ---- layer 1: out -> out (gemm reads out before gather_agg rewrites it) ----
  run_layer(out, OUT_C, W1, as1, ad1, b1, rowptr, csrsrc, N, hbuf, asN, adN, out, stream);
}